// Round 4
// baseline (3451.266 us; speedup 1.0000x reference)
//
#include <hip/hip_runtime.h>
#include <cmath>

// ---------------------------------------------------------------------------
// OmniAnomaly forward — persistent cooperative kernel, XCD-local pipeline.
//
// 256 blocks x 256 threads, 1 block/CU (151KB LDS). Blocks discover their
// physical XCD via HW_REG_XCC_ID and claim a slot 0..31 -> each XCD owns one
// 128-row batch group end-to-end. Within a group: CUs 0..15 = q-cluster
// (q-GRU + flow on CU0), CUs 16..31 = p-cluster (p-GRU + recon on 5 CUs).
//
// Phase sync (round 4): per-CLUSTER 16-CU slots+flag barrier using the
// round-2-PROVEN primitives only:
//   arrival  = __hip_atomic_store(RELAXED, AGENT) to a PRIVATE line (no RMW,
//              16 arrivals proceed in parallel -> no hot-line serialization)
//   leader   = 16 lanes poll the 16 slots in parallel (atomic RELAXED loads),
//              then stores the flag
//   follower = polls flag (read-shared line, no write contention)
// s_waitcnt vmcnt(0) before arrival (data in L2), buffer_inv (L1-only
// invalidate) after release — exactly the visibility recipe that passed
// correctness in round 2. No hand-rolled sc0 polling (round-3 hang).
//
// Cross-cluster dependency (flow z -> p-GRU) decoupled by 4-slot z buffering
// + usually-already-satisfied flag checks (>=2 phases of slack):
//   p@i reads z(i-2) written in q-phase i-1      -> need qflag >= i
//   q@i overwrites z slot (i-1)&3 (= old z(i-5),
//      read by p in phase i-3)                   -> need pflag >= i-2
//
// Software pipeline, phases i=0..102: q-step t=i | flow j=i-1 | p-step u=i-2
// | recon v=i-3. hq/hp parity-2, z parity-4. GRU carry h in registers.
// ---------------------------------------------------------------------------

#define B_  1024
#define T_  100
#define XD_ 38
#define H_  500
#define ZD_ 16
#define L_  3
#define NPHASE (T_ + 3)

typedef short bf16x8 __attribute__((ext_vector_type(8)));
typedef float f32x4  __attribute__((ext_vector_type(4)));
typedef unsigned short ushort;

#define HS ((size_t)B_ * 512)   // shorts per h buffer
#define ZS ((size_t)B_ * 32)    // shorts per z buffer

#define MFMA16(a, b, c) __builtin_amdgcn_mfma_f32_16x16x32_bf16((a), (b), (c), 0, 0, 0)

static __device__ __forceinline__ ushort f2bf(float f) {
    union { float f; unsigned u; } v; v.f = f;
    return (ushort)((v.u + 0x7FFF + ((v.u >> 16) & 1)) >> 16);   // RNE
}
static __device__ __forceinline__ float sigf(float x) { return 1.0f / (1.0f + __expf(-x)); }
static __device__ __forceinline__ float tanh_(float x) {
    float e = __expf(2.0f * x);
    return 1.0f - 2.0f / (e + 1.0f);
}
static __device__ __forceinline__ float softplus_(float x) {
    return fmaxf(x, 0.0f) + log1pf(__expf(-fabsf(x)));
}
static __device__ __forceinline__ float grp16_sum(float v) {
    v += __shfl_xor(v, 1, 16);
    v += __shfl_xor(v, 2, 16);
    v += __shfl_xor(v, 4, 16);
    v += __shfl_xor(v, 8, 16);
    return v;
}

// proven sync primitives (round 2 passed with these lowerings)
static __device__ __forceinline__ unsigned aload(const unsigned* p) {
    return __hip_atomic_load(p, __ATOMIC_RELAXED, __HIP_MEMORY_SCOPE_AGENT);
}
static __device__ __forceinline__ void astore(unsigned* p, unsigned v) {
    __hip_atomic_store(p, v, __ATOMIC_RELAXED, __HIP_MEMORY_SCOPE_AGENT);
}

struct OmniArgs {
    const float *x, *eps;
    const float *Wih_q, *Whh_q, *bih_q, *bhh_q;
    const float *Wqm, *bqm, *Wqs, *bqs;
    const float *Wih_p, *Whh_p, *bih_p, *bhh_p;
    const float *Wpm, *bpm, *Wps, *bps;
    const float *fu, *fw, *fb;
    ushort *hqbf, *hpbf, *zbf, *Wqg;
    unsigned *bar;
    float *o_rm, *o_rs, *o_z, *o_zm, *o_zs, *o_ld;
};

// 16-CU cluster barrier. slots: 16 private lines (32 uints apart); flag: one
// line. Monotonic targets -> no reset race. Same-wave exec-mask semantics
// guarantee the leader's flag store happens only after ALL 16 slot-polls exit.
static __device__ __forceinline__ void cbar(unsigned* slots, unsigned* flag,
                                            int slot, bool leader, unsigned tgt,
                                            int tid) {
    asm volatile("s_waitcnt vmcnt(0)" ::: "memory");   // my data stores are in L2
    __syncthreads();
    if (leader) {
        if (tid == 0) astore(slots + slot * 32, tgt);
        if (tid < 16) {
            const unsigned* sp = slots + tid * 32;
            while (aload(sp) < tgt) __builtin_amdgcn_s_sleep(1);
        }
        if (tid == 0) astore(flag, tgt);
    } else if (tid == 0) {
        astore(slots + slot * 32, tgt);
        while (aload(flag) < tgt) __builtin_amdgcn_s_sleep(1);
    }
    __syncthreads();
    asm volatile("buffer_inv" ::: "memory");   // L1-only invalidate
}

// usually-satisfied cross-cluster ordering check
static __device__ __forceinline__ void waitflag(const unsigned* f, int tgt, int tid) {
    if (tgt <= 0) return;
    if (tid == 0) {
        while ((int)aload(f) < tgt) __builtin_amdgcn_s_sleep(1);
    }
    __syncthreads();
    asm volatile("buffer_inv" ::: "memory");
}

__global__ __launch_bounds__(256, 1)
void omni_persist(OmniArgs A)
{
    // LDS carve (shorts): Whh 49920 | Astage 2x5120 | role tail
    __shared__ ushort lds[77440] __attribute__((aligned(16)));
    __shared__ int sh_gc[2];

    const int tid = threadIdx.x;

    // ---- discover physical XCD, claim slot 0..31 within it (one-time) ----
    if (tid == 0) {
        unsigned xcd;
        asm volatile("s_getreg_b32 %0, hwreg(HW_REG_XCC_ID)" : "=s"(xcd));
        xcd &= 7u;
        unsigned s = __hip_atomic_fetch_add(A.bar + xcd * 2048 + 1088, 1u,
                                            __ATOMIC_RELAXED, __HIP_MEMORY_SCOPE_AGENT);
        sh_gc[0] = (int)xcd;
        sh_gc[1] = (int)(s & 31u);
    }
    __syncthreads();
    const int grp = sh_gc[0];        // = physical XCD id
    const int cu  = sh_gc[1];        // 0..31 within the XCD

    unsigned* gb    = A.bar + grp * 2048;
    unsigned* qslt  = gb;            // 16 x 32 uints
    unsigned* pslt  = gb + 512;
    unsigned* qflag = gb + 1024;
    unsigned* pflag = gb + 1056;

    const bool isQ = (cu < 16);
    const int  qc  = isQ ? cu : (cu - 16);     // slice index 0..15
    const bool isFlow = (cu == 0);
    const bool isRC   = (!isQ) && (qc < 5);
    const bool isLead = (qc == 15);
    const int  m0  = grp * 128;

    unsigned* mySlots = isQ ? qslt : pslt;
    unsigned* myFlag  = isQ ? qflag : pflag;

    const int w    = tid >> 6;
    const int wm   = w & 1, wn = w >> 1;
    const int lane = tid & 63;
    const int ln   = lane & 15, qd = lane >> 4;
    const int row2 = tid >> 1;               // staging row 0..127
    const int kh   = (tid & 1) * 16;         // staging k offset

    ushort* Whl = lds;                                   // [96][520]
    ushort* As  = lds + 49920;                           // 2 x [128][40]
    ushort* Wil = lds + 60160;                           // q:[96][72] p:[96][40]
    ushort* zsl = isQ ? (lds + 67072) : (lds + 64000);   // [128][40]
    ushort* Wsl = lds + 72192;                           // flow: 2 x [32][40]
    ushort* Wrl = lds + 69120;                           // recon: [16][520]

    ushort* Wqg = A.Wqg + (size_t)grp * (32 * 544);      // per-group copy

    const int c0 = qc * 32;

    // ------------------- prologue: weights -> LDS (bf16) -------------------
    if (isQ) {
        for (int idx = tid; idx < 6*16*512; idx += 256) {
            int k = idx & 511, n = (idx >> 9) & 15, tt = idx >> 13;
            int g = tt % 3, hb = tt / 3;
            int col = c0 + hb*16 + n;
            float v = (k < H_ && col < H_) ? A.Whh_q[(size_t)(g*H_ + col)*H_ + k] : 0.f;
            Whl[(size_t)(tt*16 + n)*520 + k] = f2bf(v);
        }
        for (int idx = tid; idx < 6*16*64; idx += 256) {
            int k = idx & 63, n = (idx >> 6) & 15, tt = idx >> 10;
            int g = tt % 3, hb = tt / 3;
            int col = c0 + hb*16 + n;
            float v = (k < XD_ && col < H_) ? A.Wih_q[(size_t)(g*H_ + col)*XD_ + k] : 0.f;
            Wil[(tt*16 + n)*72 + k] = f2bf(v);
        }
        if (isFlow) {
            // Wq (mu rows 0..15, std rows 16..31) -> per-group bf16 [32][544];
            // h part at k 0..499, z part at k 512..527, zeros elsewhere.
            for (int idx = tid; idx < 32*544; idx += 256) {
                int n = idx / 544, k = idx - n*544;
                const float* src = (n < 16) ? (A.Wqm + n*(H_+ZD_)) : (A.Wqs + (n-16)*(H_+ZD_));
                float v = 0.f;
                if (k < H_) v = src[k];
                else if (k >= 512 && k < 512 + ZD_) v = src[H_ + (k - 512)];
                Wqg[idx] = f2bf(v);
            }
        }
    } else {
        for (int idx = tid; idx < 6*16*512; idx += 256) {
            int k = idx & 511, n = (idx >> 9) & 15, tt = idx >> 13;
            int g = tt % 3, hb = tt / 3;
            int col = c0 + hb*16 + n;
            float v = (k < H_ && col < H_) ? A.Whh_p[(size_t)(g*H_ + col)*H_ + k] : 0.f;
            Whl[(size_t)(tt*16 + n)*520 + k] = f2bf(v);
        }
        for (int idx = tid; idx < 6*16*32; idx += 256) {
            int k = idx & 31, n = (idx >> 5) & 15, tt = idx >> 9;
            int g = tt % 3, hb = tt / 3;
            int col = c0 + hb*16 + n;
            float v = (k < ZD_ && col < H_) ? A.Wih_p[(size_t)(g*H_ + col)*ZD_ + k] : 0.f;
            Wil[(tt*16 + n)*40 + k] = f2bf(v);
        }
        if (isRC) {
            for (int idx = tid; idx < 16*512; idx += 256) {
                int k = idx & 511, n = idx >> 9;
                int col = qc*16 + n;
                float v = 0.f;
                if (k < H_) {
                    if (col < XD_)        v = A.Wpm[(size_t)col*H_ + k];
                    else if (col < 2*XD_) v = A.Wps[(size_t)(col - XD_)*H_ + k];
                }
                Wrl[n*520 + k] = f2bf(v);
            }
        }
    }

    // per-thread constants
    const int colg = c0 + wn*16 + ln;      // GEMM epilogue h-column
    float bR = 0.f, bZ = 0.f, bNx = 0.f, bNh = 0.f;
    {
        const float* bi = isQ ? A.bih_q : A.bih_p;
        const float* bh = isQ ? A.bhh_q : A.bhh_p;
        if (colg < H_) {
            bR  = bi[colg] + bh[colg];
            bZ  = bi[H_ + colg] + bh[H_ + colg];
            bNx = bi[2*H_ + colg];
            bNh = bh[2*H_ + colg];
        }
    }
    const int colr = qc*16 + ln;           // recon column (p-side)
    float brc = 0.f;
    if (isRC) {
        if (colr < XD_) brc = A.bpm[colr];
        else if (colr < 2*XD_) brc = A.bps[colr - XD_];
    }

    float uhv[3], wvv[3], fbv[3], bqm_r = 0.f, bqs_r = 0.f;
    if (isFlow) {
        bqm_r = A.bqm[ln]; bqs_r = A.bqs[ln];
        #pragma unroll
        for (int k = 0; k < 3; ++k) {
            float w_ = A.fw[k*ZD_ + ln], u_ = A.fu[k*ZD_ + ln];
            float wu = grp16_sum(w_*u_), ww = grp16_sum(w_*w_);
            uhv[k] = u_ + (-1.f + softplus_(wu) - wu) * w_ / (ww + 1e-6f);
            wvv[k] = w_; fbv[k] = A.fb[k];
        }
    }

    float hold[16];
    #pragma unroll
    for (int r = 0; r < 16; ++r) hold[r] = 0.f;
    float ldacc[8];
    #pragma unroll
    for (int r = 0; r < 8; ++r) ldacc[r] = 0.f;

    uint4 pa0 = {0,0,0,0}, pa1 = {0,0,0,0}, pwq = {0,0,0,0};

    // ------------------------------ phases ---------------------------------
    for (int i = 0; i < NPHASE; ++i) {
        // cross-cluster ordering (usually already satisfied)
        if (isQ) waitflag(pflag, i - 2, tid);
        else     waitflag(qflag, i, tid);

        if (isQ) {
            const int t = i, j = i - 1;
            const bool do_q = (t < T_);
            const bool do_f = isFlow && (j >= 0) && (j < T_);
            if (do_q || do_f) {
                const ushort* Ag = A.hqbf + (size_t)((i-1) & 1) * HS;
                const int kt0 = (i == 0) ? 16 : 0;
                const int ktx = do_q ? 18 : 16;              // end of A-staged range
                const int ktz = (do_f && j >= 1) ? ktx : 1000;
                const int ktN = (ktz < 1000) ? (ktx + 1) : ktx;

                if (ktz < 1000) {   // pre-stage z_prev tile (flow concat input)
                    const ushort* zp = A.zbf + (size_t)((j-1) & 3)*ZS
                                     + (size_t)(m0 + row2)*32 + kh;
                    *(uint4*)&zsl[row2*40 + kh]     = *(const uint4*)zp;
                    *(uint4*)&zsl[row2*40 + kh + 8] = *(const uint4*)(zp + 8);
                }

                f32x4 aR0[4], aR1[4], aNh[4], aNx[4], aM[4], aS[4];
                #pragma unroll
                for (int mt = 0; mt < 4; ++mt) {
                    aR0[mt] = f32x4{0.f,0.f,0.f,0.f}; aR1[mt] = f32x4{0.f,0.f,0.f,0.f};
                    aNh[mt] = f32x4{0.f,0.f,0.f,0.f}; aNx[mt] = f32x4{0.f,0.f,0.f,0.f};
                    aM[mt]  = f32x4{0.f,0.f,0.f,0.f}; aS[mt]  = f32x4{0.f,0.f,0.f,0.f};
                }

                auto loadq = [&](int kt) {
                    if (kt < 16) {
                        const ushort* s = Ag + (size_t)(m0 + row2)*512 + kt*32 + kh;
                        pa0 = *(const uint4*)s;
                        pa1 = *(const uint4*)(s + 8);
                    } else if (kt < ktx) {   // x tile, on-the-fly f32->bf16
                        const float* xs = A.x + ((size_t)(m0 + row2)*T_ + t)*XD_;
                        int kb = (kt - 16)*32 + kh;
                        unsigned pk8[8];
                        #pragma unroll
                        for (int ii = 0; ii < 8; ++ii) {
                            int d = kb + ii*2;
                            float v0 = 0.f, v1 = 0.f;
                            if (d + 1 < XD_) { float2 f = *(const float2*)(xs + d); v0 = f.x; v1 = f.y; }
                            else if (d < XD_) v0 = xs[d];
                            pk8[ii] = (unsigned)f2bf(v0) | ((unsigned)f2bf(v1) << 16);
                        }
                        pa0 = make_uint4(pk8[0], pk8[1], pk8[2], pk8[3]);
                        pa1 = make_uint4(pk8[4], pk8[5], pk8[6], pk8[7]);
                    }
                    if (do_f && tid < 128) {
                        int wk = (kt < 16) ? kt : ((kt == ktz) ? 16 : -1);
                        if (wk >= 0)
                            pwq = *(const uint4*)(Wqg + (size_t)(tid >> 2)*544
                                                  + wk*32 + (tid & 3)*8);
                    }
                };

                loadq(kt0);
                for (int kt = kt0; kt < ktN; ++kt) {
                    const int buf = kt & 1;
                    ushort* Ab = As + buf*5120;
                    if (kt < ktx) {
                        *(uint4*)&Ab[row2*40 + kh]     = pa0;
                        *(uint4*)&Ab[row2*40 + kh + 8] = pa1;
                    }
                    if (do_f && tid < 128) {
                        int wk = (kt < 16) ? kt : ((kt == ktz) ? 16 : -1);
                        if (wk >= 0)
                            *(uint4*)&Wsl[buf*1280 + (tid >> 2)*40 + (tid & 3)*8] = pwq;
                    }
                    __syncthreads();
                    if (kt + 1 < ktN) loadq(kt + 1);

                    bf16x8 af[4];
                    if (kt < ktx) {
                        #pragma unroll
                        for (int mt = 0; mt < 4; ++mt)
                            af[mt] = *(const bf16x8*)&Ab[(wm*64 + mt*16 + ln)*40 + qd*8];
                    }
                    if (do_q && kt < ktx) {
                        bf16x8 b0, b1, b2;
                        if (kt < 16) {
                            const ushort* wb = Whl + (size_t)(wn*48 + ln)*520 + kt*32 + qd*8;
                            b0 = *(const bf16x8*)(wb);
                            b1 = *(const bf16x8*)(wb + 16*520);
                            b2 = *(const bf16x8*)(wb + 32*520);
                        } else {
                            const ushort* wb = Wil + (size_t)(wn*48 + ln)*72 + (kt-16)*32 + qd*8;
                            b0 = *(const bf16x8*)(wb);
                            b1 = *(const bf16x8*)(wb + 16*72);
                            b2 = *(const bf16x8*)(wb + 32*72);
                        }
                        #pragma unroll
                        for (int mt = 0; mt < 4; ++mt) {
                            aR0[mt] = MFMA16(af[mt], b0, aR0[mt]);
                            aR1[mt] = MFMA16(af[mt], b1, aR1[mt]);
                        }
                        if (kt < 16) {
                            #pragma unroll
                            for (int mt = 0; mt < 4; ++mt) aNh[mt] = MFMA16(af[mt], b2, aNh[mt]);
                        } else {
                            #pragma unroll
                            for (int mt = 0; mt < 4; ++mt) aNx[mt] = MFMA16(af[mt], b2, aNx[mt]);
                        }
                    }
                    if (do_f && wn == 1 && (kt < 16 || kt == ktz)) {
                        bf16x8 am[4];
                        if (kt == ktz) {
                            #pragma unroll
                            for (int mt = 0; mt < 4; ++mt)
                                am[mt] = *(const bf16x8*)&zsl[(wm*64 + mt*16 + ln)*40 + qd*8];
                        } else {
                            #pragma unroll
                            for (int mt = 0; mt < 4; ++mt) am[mt] = af[mt];
                        }
                        bf16x8 bM = *(const bf16x8*)&Wsl[buf*1280 + ln*40 + qd*8];
                        bf16x8 bS = *(const bf16x8*)&Wsl[buf*1280 + (16 + ln)*40 + qd*8];
                        #pragma unroll
                        for (int mt = 0; mt < 4; ++mt) {
                            aM[mt] = MFMA16(am[mt], bM, aM[mt]);
                            aS[mt] = MFMA16(am[mt], bS, aS[mt]);
                        }
                    }
                }

                // ---- q-GRU epilogue (carry in registers) ----
                if (do_q) {
                    ushort* Hb = A.hqbf + (size_t)(i & 1) * HS;
                    #pragma unroll
                    for (int mt = 0; mt < 4; ++mt)
                        #pragma unroll
                        for (int r = 0; r < 4; ++r) {
                            int row = m0 + wm*64 + mt*16 + qd*4 + r;
                            float rg = sigf(aR0[mt][r] + bR);
                            float zg = sigf(aR1[mt][r] + bZ);
                            float ng = tanh_(aNx[mt][r] + bNx + rg*(aNh[mt][r] + bNh));
                            float hn = (1.f - zg)*ng + zg*hold[mt*4 + r];
                            if (colg >= H_) hn = 0.f;
                            hold[mt*4 + r] = hn;
                            Hb[(size_t)row*512 + colg] = f2bf(hn);
                        }
                }
                // ---- flow epilogue: redistribute mu/std via LDS, all 256 threads ----
                if (do_f) {
                    __syncthreads();
                    float* Sf = (float*)As;   // As is dead now; 128x32 f32 = 16 KB
                    if (wn == 1) {
                        #pragma unroll
                        for (int mt = 0; mt < 4; ++mt)
                            #pragma unroll
                            for (int r = 0; r < 4; ++r) {
                                int rowl = wm*64 + mt*16 + qd*4 + r;
                                Sf[rowl*32 + ln]      = aM[mt][r];
                                Sf[rowl*32 + 16 + ln] = aS[mt][r];
                            }
                    }
                    __syncthreads();
                    ushort* Zo = A.zbf + (size_t)(j & 3) * ZS;
                    #pragma unroll
                    for (int s8 = 0; s8 < 8; ++s8) {
                        int rowl = (tid >> 4)*8 + s8;
                        int row  = m0 + rowl;
                        float mu = Sf[rowl*32 + ln] + bqm_r;
                        float sd = softplus_(Sf[rowl*32 + 16 + ln] + bqs_r) + 1e-4f;
                        size_t oi = ((size_t)row*T_ + j)*ZD_ + ln;
                        float zk = mu + A.eps[oi]*sd;
                        A.o_zm[oi] = mu;
                        A.o_zs[oi] = sd;
                        float lsum = 0.f;
                        #pragma unroll
                        for (int k = 0; k < 3; ++k) {
                            float th = tanh_(grp16_sum(zk*wvv[k]) + fbv[k]);
                            zk = fmaf(uhv[k], th, zk);
                            float det = 1.f + grp16_sum((1.f - th*th)*wvv[k]*uhv[k]);
                            lsum += logf(fabsf(det) + 1e-6f);
                        }
                        A.o_z[oi] = zk;
                        Zo[(size_t)row*32 + ln]      = f2bf(zk);
                        Zo[(size_t)row*32 + 16 + ln] = 0;
                        ldacc[s8] += lsum;
                        if (j == T_ - 1 && ln == 0) A.o_ld[row] = ldacc[s8];
                    }
                }
            }
        } else {
            // ------------------------- p-side -------------------------
            const int u = i - 2, v = i - 3;
            const bool do_p = (u >= 0) && (u < T_);
            const bool do_r = isRC && (v >= 0) && (v < T_);
            if (do_p || do_r) {
                const ushort* Ag = A.hpbf + (size_t)((i-1) & 1) * HS;
                const ushort* Zg = A.zbf + (size_t)(u & 3) * ZS;
                const int kt0 = (do_p && u == 0) ? 16 : 0;
                const int ktN = do_p ? 17 : 16;

                f32x4 aR0[4], aR1[4], aNh[4], aNx[4], aC[4];
                #pragma unroll
                for (int mt = 0; mt < 4; ++mt) {
                    aR0[mt] = f32x4{0.f,0.f,0.f,0.f}; aR1[mt] = f32x4{0.f,0.f,0.f,0.f};
                    aNh[mt] = f32x4{0.f,0.f,0.f,0.f}; aNx[mt] = f32x4{0.f,0.f,0.f,0.f};
                    aC[mt]  = f32x4{0.f,0.f,0.f,0.f};
                }

                auto loadp = [&](int kt) {
                    if (kt < 16) {
                        const ushort* s = Ag + (size_t)(m0 + row2)*512 + kt*32 + kh;
                        pa0 = *(const uint4*)s; pa1 = *(const uint4*)(s + 8);
                    } else {
                        const ushort* s = Zg + (size_t)(m0 + row2)*32 + kh;
                        pa0 = *(const uint4*)s; pa1 = *(const uint4*)(s + 8);
                    }
                };

                loadp(kt0);
                for (int kt = kt0; kt < ktN; ++kt) {
                    const int buf = kt & 1;
                    ushort* Ab = As + buf*5120;
                    *(uint4*)&Ab[row2*40 + kh]     = pa0;
                    *(uint4*)&Ab[row2*40 + kh + 8] = pa1;
                    __syncthreads();
                    if (kt + 1 < ktN) loadp(kt + 1);

                    bf16x8 af[4];
                    #pragma unroll
                    for (int mt = 0; mt < 4; ++mt)
                        af[mt] = *(const bf16x8*)&Ab[(wm*64 + mt*16 + ln)*40 + qd*8];

                    if (do_p) {
                        bf16x8 b0, b1, b2;
                        if (kt < 16) {
                            const ushort* wb = Whl + (size_t)(wn*48 + ln)*520 + kt*32 + qd*8;
                            b0 = *(const bf16x8*)(wb);
                            b1 = *(const bf16x8*)(wb + 16*520);
                            b2 = *(const bf16x8*)(wb + 32*520);
                        } else {
                            const ushort* wb = Wil + (size_t)(wn*48 + ln)*40 + qd*8;
                            b0 = *(const bf16x8*)(wb);
                            b1 = *(const bf16x8*)(wb + 16*40);
                            b2 = *(const bf16x8*)(wb + 32*40);
                        }
                        #pragma unroll
                        for (int mt = 0; mt < 4; ++mt) {
                            aR0[mt] = MFMA16(af[mt], b0, aR0[mt]);
                            aR1[mt] = MFMA16(af[mt], b1, aR1[mt]);
                        }
                        if (kt < 16) {
                            #pragma unroll
                            for (int mt = 0; mt < 4; ++mt) aNh[mt] = MFMA16(af[mt], b2, aNh[mt]);
                        } else {
                            #pragma unroll
                            for (int mt = 0; mt < 4; ++mt) aNx[mt] = MFMA16(af[mt], b2, aNx[mt]);
                        }
                    }
                    if (do_r && kt < 16 && wn == 1) {
                        bf16x8 b = *(const bf16x8*)&Wrl[ln*520 + kt*32 + qd*8];
                        #pragma unroll
                        for (int mt = 0; mt < 4; ++mt) aC[mt] = MFMA16(af[mt], b, aC[mt]);
                    }
                }

                if (do_p) {
                    ushort* Hb = A.hpbf + (size_t)(i & 1) * HS;
                    #pragma unroll
                    for (int mt = 0; mt < 4; ++mt)
                        #pragma unroll
                        for (int r = 0; r < 4; ++r) {
                            int row = m0 + wm*64 + mt*16 + qd*4 + r;
                            float rg = sigf(aR0[mt][r] + bR);
                            float zg = sigf(aR1[mt][r] + bZ);
                            float ng = tanh_(aNx[mt][r] + bNx + rg*(aNh[mt][r] + bNh));
                            float hn = (1.f - zg)*ng + zg*hold[mt*4 + r];
                            if (colg >= H_) hn = 0.f;
                            hold[mt*4 + r] = hn;
                            Hb[(size_t)row*512 + colg] = f2bf(hn);
                        }
                }
                if (do_r && wn == 1) {
                    #pragma unroll
                    for (int mt = 0; mt < 4; ++mt)
                        #pragma unroll
                        for (int r = 0; r < 4; ++r) {
                            int row = m0 + wm*64 + mt*16 + qd*4 + r;
                            size_t ob = ((size_t)row*T_ + v)*XD_;
                            float a = aC[mt][r];
                            if (colr < XD_)        A.o_rm[ob + colr] = a + brc;
                            else if (colr < 2*XD_) A.o_rs[ob + (colr - XD_)] =
                                                       softplus_(a + brc) + 1e-4f;
                        }
                }
            }
        }
        if (i < NPHASE - 1)
            cbar(mySlots, myFlag, qc, isLead, (unsigned)(i + 1), tid);
    }
}

// ---------------------------------------------------------------------------
extern "C" void kernel_launch(void* const* d_in, const int* in_sizes, int n_in,
                              void* d_out, int out_size, void* d_ws, size_t ws_size,
                              hipStream_t stream)
{
    (void)in_sizes; (void)n_in; (void)out_size; (void)ws_size;
    float* out = (float*)d_out;

    char* p = (char*)d_ws;
    auto alloc = [&](size_t bytes) { void* r = p; p += (bytes + 255) & ~(size_t)255; return r; };
    const size_t HSb = (size_t)1024 * 512 * sizeof(ushort);
    ushort* hqbf = (ushort*)alloc(2 * HSb);
    ushort* hpbf = (ushort*)alloc(2 * HSb);
    ushort* zbf  = (ushort*)alloc(4 * (size_t)1024 * 32 * sizeof(ushort));
    ushort* Wqg  = (ushort*)alloc((size_t)8 * 32 * 544 * sizeof(ushort));
    unsigned* bar = (unsigned*)alloc((size_t)8 * 2048 * sizeof(unsigned));

    hipMemsetAsync(bar, 0, (size_t)8 * 2048 * sizeof(unsigned), stream);

    OmniArgs a;
    a.x     = (const float*)d_in[0];
    a.eps   = (const float*)d_in[1];
    a.Wih_q = (const float*)d_in[2];
    a.Whh_q = (const float*)d_in[3];
    a.bih_q = (const float*)d_in[4];
    a.bhh_q = (const float*)d_in[5];
    a.Wqm   = (const float*)d_in[6];
    a.bqm   = (const float*)d_in[7];
    a.Wqs   = (const float*)d_in[8];
    a.bqs   = (const float*)d_in[9];
    a.Wih_p = (const float*)d_in[10];
    a.Whh_p = (const float*)d_in[11];
    a.bih_p = (const float*)d_in[12];
    a.bhh_p = (const float*)d_in[13];
    a.Wpm   = (const float*)d_in[14];
    a.bpm   = (const float*)d_in[15];
    a.Wps   = (const float*)d_in[16];
    a.bps   = (const float*)d_in[17];
    a.fu    = (const float*)d_in[18];
    a.fw    = (const float*)d_in[19];
    a.fb    = (const float*)d_in[20];
    a.hqbf = hqbf; a.hpbf = hpbf; a.zbf = zbf; a.Wqg = Wqg; a.bar = bar;
    a.o_rm = out;
    a.o_rs = out + 3891200;
    a.o_z  = out + 7782400;
    a.o_zm = out + 9420800;
    a.o_zs = out + 11059200;
    a.o_ld = out + 12697600;

    void* kargs[] = { &a };
    hipError_t err = hipLaunchCooperativeKernel((void*)omni_persist, dim3(256), dim3(256),
                                                kargs, 0, stream);
    if (err != hipSuccess) {
        // fallback: plain launch — grid == CU count, 1 block/CU (151 KB LDS),
        // so all 256 workgroups are co-resident.
        (void)hipGetLastError();
        hipLaunchKernelGGL(omni_persist, dim3(256), dim3(256), 0, stream, a);
    }
}

// Round 5
// 2725.270 us; speedup vs baseline: 1.2664x; 1.2664x over previous
//
#include <hip/hip_runtime.h>
#include <cmath>

// ---------------------------------------------------------------------------
// OmniAnomaly forward — persistent cooperative kernel, fused q+p per CU.
//
// 256 blocks x 512 threads (8 waves), 1 block/CU (148KB LDS). Blocks find
// their physical XCD (HW_REG_XCC_ID) and claim slot 0..31; each XCD owns one
// 128-row batch group. Each CU owns a 16-col slice of BOTH GRUs:
//   waves 0..3 = q-GEMM (+ flow on CU31), waves 4..7 = p-GEMM (+ recon on
//   CUs 0..4). Two independent GEMM streams per CU -> 2x memory-level
//   parallelism; 8 waves -> 2x latency hiding vs round 4.
//
// ONE 32-CU barrier per phase (slots+flag, relaxed agent atomics +
// vmcnt(0) + L1 buffer_inv — the proven recipe). No cross-cluster waits:
// all dependencies are "previous phase":
//   phase i: q-step t=i | flow j=i-1 (CU31) | p-step u=i-2 | recon v=i-3
//   hq/hp/z all parity-2. GRU carry h in registers.
// Flow/recon B-fragments and the flow z A-fragment are direct global reads
// (16B/lane aligned, L2-hot) — no LDS staging for them.
// ---------------------------------------------------------------------------

#define B_  1024
#define T_  100
#define XD_ 38
#define H_  500
#define ZD_ 16
#define L_  3
#define NPHASE (T_ + 3)

typedef short bf16x8 __attribute__((ext_vector_type(8)));
typedef float f32x4  __attribute__((ext_vector_type(4)));
typedef unsigned short ushort;

#define HS ((size_t)B_ * 512)   // shorts per h buffer
#define ZS ((size_t)B_ * 32)    // shorts per z buffer

#define MFMA16(a, b, c) __builtin_amdgcn_mfma_f32_16x16x32_bf16((a), (b), (c), 0, 0, 0)

static __device__ __forceinline__ ushort f2bf(float f) {
    union { float f; unsigned u; } v; v.f = f;
    return (ushort)((v.u + 0x7FFF + ((v.u >> 16) & 1)) >> 16);   // RNE
}
static __device__ __forceinline__ float sigf(float x) { return 1.0f / (1.0f + __expf(-x)); }
static __device__ __forceinline__ float tanh_(float x) {
    float e = __expf(2.0f * x);
    return 1.0f - 2.0f / (e + 1.0f);
}
static __device__ __forceinline__ float softplus_(float x) {
    return fmaxf(x, 0.0f) + log1pf(__expf(-fabsf(x)));
}
static __device__ __forceinline__ float grp16_sum(float v) {
    v += __shfl_xor(v, 1, 16);
    v += __shfl_xor(v, 2, 16);
    v += __shfl_xor(v, 4, 16);
    v += __shfl_xor(v, 8, 16);
    return v;
}

// proven sync primitives (rounds 2/4 passed with these lowerings)
static __device__ __forceinline__ unsigned aload(const unsigned* p) {
    return __hip_atomic_load(p, __ATOMIC_RELAXED, __HIP_MEMORY_SCOPE_AGENT);
}
static __device__ __forceinline__ void astore(unsigned* p, unsigned v) {
    __hip_atomic_store(p, v, __ATOMIC_RELAXED, __HIP_MEMORY_SCOPE_AGENT);
}

struct OmniArgs {
    const float *x, *eps;
    const float *Wih_q, *Whh_q, *bih_q, *bhh_q;
    const float *Wqm, *bqm, *Wqs, *bqs;
    const float *Wih_p, *Whh_p, *bih_p, *bhh_p;
    const float *Wpm, *bpm, *Wps, *bps;
    const float *fu, *fw, *fb;
    ushort *hqbf, *hpbf, *zbf, *Wqg, *Wpg;
    unsigned *bar;
    float *o_rm, *o_rs, *o_z, *o_zm, *o_zs, *o_ld;
};

// 32-CU XCD-local barrier: private arrival lines + shared flag. Monotonic
// targets, relaxed agent atomics, vmcnt(0) before arrival (data in L2),
// L1-only buffer_inv after release.
static __device__ __forceinline__ void cbar32(unsigned* slots, unsigned* flag,
                                              int slot, bool leader, unsigned tgt,
                                              int tid) {
    asm volatile("s_waitcnt vmcnt(0)" ::: "memory");
    __syncthreads();
    if (leader) {
        if (tid == 0) astore(slots + slot * 32, tgt);
        if (tid < 32) {
            const unsigned* sp = slots + tid * 32;
            while (aload(sp) < tgt) __builtin_amdgcn_s_sleep(1);
        }
        if (tid == 0) astore(flag, tgt);
    } else if (tid == 0) {
        astore(slots + slot * 32, tgt);
        while (aload(flag) < tgt) __builtin_amdgcn_s_sleep(1);
    }
    __syncthreads();
    asm volatile("buffer_inv" ::: "memory");   // L1-only invalidate
}

__global__ __launch_bounds__(512)
void omni_persist(OmniArgs A)
{
    // LDS carve (shorts):
    //  WhlQ [48][520] @0      | WhlP [48][520] @24960
    //  WilQ [48][72]  @49920  | WilP [48][40]  @53376
    //  AsQ 2x5120     @55296  | AsP 2x5120     @65536   (total 75776 = 148KB)
    __shared__ ushort lds[75776] __attribute__((aligned(16)));
    __shared__ int sh_gc[2];

    const int tid = threadIdx.x;

    // ---- discover physical XCD, claim slot 0..31 (one-time) ----
    if (tid == 0) {
        unsigned xcd;
        asm volatile("s_getreg_b32 %0, hwreg(HW_REG_XCC_ID)" : "=s"(xcd));
        xcd &= 7u;
        unsigned s = __hip_atomic_fetch_add(A.bar + xcd * 2048 + 1152, 1u,
                                            __ATOMIC_RELAXED, __HIP_MEMORY_SCOPE_AGENT);
        sh_gc[0] = (int)xcd;
        sh_gc[1] = (int)(s & 31u);
    }
    __syncthreads();
    const int grp = sh_gc[0];
    const int qc  = sh_gc[1];              // 0..31
    unsigned* slots = A.bar + grp * 2048;
    unsigned* flag  = slots + 1024;

    const bool isFlowCU = (qc == 31);      // flow on CU31 (recon is on 0..4)
    const bool isRC     = (qc < 5);
    const bool isLead   = (qc == 15);
    const int  m0 = grp * 128;

    const int gtid = tid & 255;            // index within wave-group
    const bool isQg = (tid < 256);         // waves 0..3 = q, 4..7 = p
    const int w2   = gtid >> 6;            // wave-in-group 0..3
    const int lane = tid & 63;
    const int ln   = lane & 15, qd = lane >> 4;
    const int row2 = gtid >> 1;            // staging row 0..127
    const int kh   = (gtid & 1) * 16;      // staging k offset

    ushort* Whl = lds + (isQg ? 0 : 24960);          // [48][520] own GRU
    ushort* Wil = lds + (isQg ? 49920 : 53376);      // q:[48][72] p:[48][40]
    ushort* As  = lds + (isQg ? 55296 : 65536);      // 2 x [128][40]
    const int wilS = isQg ? 72 : 40;

    ushort* WqgG = A.Wqg + (size_t)grp * (32 * 544);
    ushort* WpgG = A.Wpg + (size_t)grp * (128 * 512);

    // ------------------- prologue: weights -> LDS / global bf16 ------------
    {
        const float* WhhSrc = isQg ? A.Whh_q : A.Whh_p;
        for (int idx = gtid; idx < 3*16*512; idx += 256) {
            int k = idx & 511, n = (idx >> 9) & 15, g = idx >> 13;
            int col = qc*16 + n;
            float v = (k < H_ && col < H_) ? WhhSrc[(size_t)(g*H_ + col)*H_ + k] : 0.f;
            Whl[(g*16 + n)*520 + k] = f2bf(v);
        }
        if (isQg) {
            for (int idx = gtid; idx < 3*16*64; idx += 256) {
                int k = idx & 63, n = (idx >> 6) & 15, g = idx >> 10;
                int col = qc*16 + n;
                float v = (k < XD_ && col < H_) ? A.Wih_q[(size_t)(g*H_+col)*XD_ + k] : 0.f;
                Wil[(g*16 + n)*72 + k] = f2bf(v);
            }
            if (isFlowCU) {
                // Wq heads -> per-group bf16 [32][544] (h @0..499, z @512..527)
                for (int idx = gtid; idx < 32*544; idx += 256) {
                    int n = idx / 544, k = idx - n*544;
                    const float* src = (n < 16) ? (A.Wqm + n*(H_+ZD_))
                                                : (A.Wqs + (n-16)*(H_+ZD_));
                    float v = 0.f;
                    if (k < H_) v = src[k];
                    else if (k >= 512 && k < 512 + ZD_) v = src[H_ + (k - 512)];
                    WqgG[idx] = f2bf(v);
                }
            }
        } else {
            for (int idx = gtid; idx < 3*16*32; idx += 256) {
                int k = idx & 31, n = (idx >> 5) & 15, g = idx >> 9;
                int col = qc*16 + n;
                float v = (k < ZD_ && col < H_) ? A.Wih_p[(size_t)(g*H_+col)*ZD_ + k] : 0.f;
                Wil[(g*16 + n)*40 + k] = f2bf(v);
            }
            if (isRC) {
                // recon head rows qc*16..+16 -> per-group bf16 [128][512]
                for (int idx = gtid; idx < 16*512; idx += 256) {
                    int k = idx & 511, n = idx >> 9;
                    int col = qc*16 + n;
                    float v = 0.f;
                    if (k < H_) {
                        if (col < XD_)        v = A.Wpm[(size_t)col*H_ + k];
                        else if (col < 2*XD_) v = A.Wps[(size_t)(col - XD_)*H_ + k];
                    }
                    WpgG[(size_t)(qc*16 + n)*512 + k] = f2bf(v);
                }
            }
        }
    }

    // per-thread constants
    const int colg = qc*16 + ln;           // GRU epilogue h-column
    float bR = 0.f, bZ = 0.f, bNx = 0.f, bNh = 0.f;
    {
        const float* bi = isQg ? A.bih_q : A.bih_p;
        const float* bh = isQg ? A.bhh_q : A.bhh_p;
        if (colg < H_) {
            bR  = bi[colg] + bh[colg];
            bZ  = bi[H_ + colg] + bh[H_ + colg];
            bNx = bi[2*H_ + colg];
            bNh = bh[2*H_ + colg];
        }
    }
    const int colr = qc*16 + ln;           // recon column (p-group, RC CUs)
    float brc = 0.f;
    if (isRC && !isQg) {
        if (colr < XD_) brc = A.bpm[colr];
        else if (colr < 2*XD_) brc = A.bps[colr - XD_];
    }

    float uhv[3], wvv[3], fbv[3], bqm_r = 0.f, bqs_r = 0.f;
    const int zd = gtid & 15;
    if (isFlowCU && isQg) {
        bqm_r = A.bqm[zd]; bqs_r = A.bqs[zd];
        #pragma unroll
        for (int k = 0; k < 3; ++k) {
            float w_ = A.fw[k*ZD_ + zd], u_ = A.fu[k*ZD_ + zd];
            float wu = grp16_sum(w_*u_), ww = grp16_sum(w_*w_);
            uhv[k] = u_ + (-1.f + softplus_(wu) - wu) * w_ / (ww + 1e-6f);
            wvv[k] = w_; fbv[k] = A.fb[k];
        }
    }

    float hold[8];
    #pragma unroll
    for (int r = 0; r < 8; ++r) hold[r] = 0.f;
    float ldacc[8];
    #pragma unroll
    for (int r = 0; r < 8; ++r) ldacc[r] = 0.f;

    __syncthreads();   // LDS weights visible to all waves

    uint4 pa0 = {0,0,0,0}, pa1 = {0,0,0,0};

    // ------------------------------ phases ---------------------------------
    for (int i = 0; i < NPHASE; ++i) {
        const int t = i, j = i - 1, u = i - 2, v = i - 3;
        const bool do_q = (t < T_);
        const bool do_f = isFlowCU && (j >= 0) && (j < T_);
        const bool do_p = (u >= 0) && (u < T_);
        const bool do_r = isRC && (v >= 0) && (v < T_);

        const int qNeed = do_q ? 18 : (do_f ? 16 : 0);
        const int pNeed = do_p ? 17 : (do_r ? 16 : 0);
        const int ktMax = qNeed > pNeed ? qNeed : pNeed;
        const int ktLo  = (i == 0) ? 16 : 0;

        const ushort* AgQ = A.hqbf + (size_t)((i-1) & 1) * HS;
        const ushort* AgP = A.hpbf + (size_t)((i-1) & 1) * HS;
        const ushort* ZgP = A.zbf  + (size_t)(u & 1) * ZS;

        auto stagePred = [&](int kt) -> bool {
            if (isQg) {
                if (do_q) return (i == 0) ? (kt >= 16 && kt < 18) : (kt < 18);
                return do_f && kt < 16;
            } else {
                if (do_p) return (u == 0) ? (kt == 16) : (kt < 17);
                return do_r && kt < 16;
            }
        };
        auto loadA = [&](int kt) {
            if (!stagePred(kt)) return;
            if (isQg) {
                if (kt < 16) {
                    const ushort* s = AgQ + (size_t)(m0 + row2)*512 + kt*32 + kh;
                    pa0 = *(const uint4*)s; pa1 = *(const uint4*)(s + 8);
                } else {                      // x tile, f32 -> bf16 pack
                    const float* xs = A.x + ((size_t)(m0 + row2)*T_ + t)*XD_;
                    int kb = (kt - 16)*32 + kh;
                    unsigned pk8[8];
                    #pragma unroll
                    for (int ii = 0; ii < 8; ++ii) {
                        int d = kb + ii*2;
                        float v0 = 0.f, v1 = 0.f;
                        if (d + 1 < XD_) { float2 f = *(const float2*)(xs + d); v0 = f.x; v1 = f.y; }
                        else if (d < XD_) v0 = xs[d];
                        pk8[ii] = (unsigned)f2bf(v0) | ((unsigned)f2bf(v1) << 16);
                    }
                    pa0 = make_uint4(pk8[0], pk8[1], pk8[2], pk8[3]);
                    pa1 = make_uint4(pk8[4], pk8[5], pk8[6], pk8[7]);
                }
            } else {
                const ushort* s = (kt < 16)
                    ? (AgP + (size_t)(m0 + row2)*512 + kt*32 + kh)
                    : (ZgP + (size_t)(m0 + row2)*32 + kh);
                pa0 = *(const uint4*)s; pa1 = *(const uint4*)(s + 8);
            }
        };

        f32x4 aR0[2], aR1[2], aNh[2], aNx[2], aM[2], aS[2], aC[2];
        #pragma unroll
        for (int mt = 0; mt < 2; ++mt) {
            aR0[mt] = f32x4{0.f,0.f,0.f,0.f}; aR1[mt] = f32x4{0.f,0.f,0.f,0.f};
            aNh[mt] = f32x4{0.f,0.f,0.f,0.f}; aNx[mt] = f32x4{0.f,0.f,0.f,0.f};
            aM[mt]  = f32x4{0.f,0.f,0.f,0.f}; aS[mt]  = f32x4{0.f,0.f,0.f,0.f};
            aC[mt]  = f32x4{0.f,0.f,0.f,0.f};
        }

        if (ktLo < ktMax) loadA(ktLo);
        for (int kt = ktLo; kt < ktMax; ++kt) {
            const int buf = kt & 1;
            ushort* Ab = As + buf*5120;
            const bool sp = stagePred(kt);
            if (sp) {
                *(uint4*)&Ab[row2*40 + kh]     = pa0;
                *(uint4*)&Ab[row2*40 + kh + 8] = pa1;
            }
            __syncthreads();
            if (kt + 1 < ktMax) loadA(kt + 1);

            bf16x8 af[2];
            if (sp) {
                #pragma unroll
                for (int mt = 0; mt < 2; ++mt)
                    af[mt] = *(const bf16x8*)&Ab[(w2*32 + mt*16 + ln)*40 + qd*8];
            }
            if (isQg) {
                if (do_q && sp) {
                    bf16x8 b0, b1, b2;
                    if (kt < 16) {
                        const ushort* wb = Whl + (size_t)ln*520 + kt*32 + qd*8;
                        b0 = *(const bf16x8*)(wb);
                        b1 = *(const bf16x8*)(wb + 16*520);
                        b2 = *(const bf16x8*)(wb + 32*520);
                    } else {
                        const ushort* wb = Wil + (size_t)ln*72 + (kt-16)*32 + qd*8;
                        b0 = *(const bf16x8*)(wb);
                        b1 = *(const bf16x8*)(wb + 16*72);
                        b2 = *(const bf16x8*)(wb + 32*72);
                    }
                    #pragma unroll
                    for (int mt = 0; mt < 2; ++mt) {
                        aR0[mt] = MFMA16(af[mt], b0, aR0[mt]);
                        aR1[mt] = MFMA16(af[mt], b1, aR1[mt]);
                    }
                    if (kt < 16) {
                        #pragma unroll
                        for (int mt = 0; mt < 2; ++mt) aNh[mt] = MFMA16(af[mt], b2, aNh[mt]);
                    } else {
                        #pragma unroll
                        for (int mt = 0; mt < 2; ++mt) aNx[mt] = MFMA16(af[mt], b2, aNx[mt]);
                    }
                }
                if (do_f && kt < 16) {     // flow heads, B direct from L2
                    bf16x8 bM = *(const bf16x8*)(WqgG + (size_t)ln*544 + kt*32 + qd*8);
                    bf16x8 bS = *(const bf16x8*)(WqgG + (size_t)(16+ln)*544 + kt*32 + qd*8);
                    #pragma unroll
                    for (int mt = 0; mt < 2; ++mt) {
                        aM[mt] = MFMA16(af[mt], bM, aM[mt]);
                        aS[mt] = MFMA16(af[mt], bS, aS[mt]);
                    }
                }
            } else {
                if (do_p && sp) {
                    bf16x8 b0, b1, b2;
                    if (kt < 16) {
                        const ushort* wb = Whl + (size_t)ln*520 + kt*32 + qd*8;
                        b0 = *(const bf16x8*)(wb);
                        b1 = *(const bf16x8*)(wb + 16*520);
                        b2 = *(const bf16x8*)(wb + 32*520);
                    } else {
                        const ushort* wb = Wil + (size_t)ln*40 + qd*8;
                        b0 = *(const bf16x8*)(wb);
                        b1 = *(const bf16x8*)(wb + 16*40);
                        b2 = *(const bf16x8*)(wb + 32*40);
                    }
                    #pragma unroll
                    for (int mt = 0; mt < 2; ++mt) {
                        aR0[mt] = MFMA16(af[mt], b0, aR0[mt]);
                        aR1[mt] = MFMA16(af[mt], b1, aR1[mt]);
                    }
                    if (kt < 16) {
                        #pragma unroll
                        for (int mt = 0; mt < 2; ++mt) aNh[mt] = MFMA16(af[mt], b2, aNh[mt]);
                    } else {
                        #pragma unroll
                        for (int mt = 0; mt < 2; ++mt) aNx[mt] = MFMA16(af[mt], b2, aNx[mt]);
                    }
                }
                if (do_r && kt < 16) {     // recon head, B direct from L2
                    bf16x8 b = *(const bf16x8*)(WpgG + (size_t)(qc*16+ln)*512 + kt*32 + qd*8);
                    #pragma unroll
                    for (int mt = 0; mt < 2; ++mt) aC[mt] = MFMA16(af[mt], b, aC[mt]);
                }
            }
        }

        // ---- flow z-concat step (A and B direct from L2) ----
        if (do_f && isQg && j >= 1) {
            const ushort* zp = A.zbf + (size_t)((j-1) & 1) * ZS;
            bf16x8 bM = *(const bf16x8*)(WqgG + (size_t)ln*544 + 512 + qd*8);
            bf16x8 bS = *(const bf16x8*)(WqgG + (size_t)(16+ln)*544 + 512 + qd*8);
            #pragma unroll
            for (int mt = 0; mt < 2; ++mt) {
                bf16x8 am = *(const bf16x8*)(zp + (size_t)(m0 + w2*32 + mt*16 + ln)*32 + qd*8);
                aM[mt] = MFMA16(am, bM, aM[mt]);
                aS[mt] = MFMA16(am, bS, aS[mt]);
            }
        }

        // ---- GRU epilogues (carry in registers) ----
        if (isQg && do_q) {
            ushort* Hb = A.hqbf + (size_t)(i & 1) * HS;
            #pragma unroll
            for (int mt = 0; mt < 2; ++mt)
                #pragma unroll
                for (int r = 0; r < 4; ++r) {
                    int row = m0 + w2*32 + mt*16 + qd*4 + r;
                    float rg = sigf(aR0[mt][r] + bR);
                    float zg = sigf(aR1[mt][r] + bZ);
                    float ng = tanh_(aNx[mt][r] + bNx + rg*(aNh[mt][r] + bNh));
                    float hn = (1.f - zg)*ng + zg*hold[mt*4 + r];
                    if (colg >= H_) hn = 0.f;
                    hold[mt*4 + r] = hn;
                    Hb[(size_t)row*512 + colg] = f2bf(hn);
                }
        }
        if (!isQg && do_p) {
            ushort* Hb = A.hpbf + (size_t)(i & 1) * HS;
            #pragma unroll
            for (int mt = 0; mt < 2; ++mt)
                #pragma unroll
                for (int r = 0; r < 4; ++r) {
                    int row = m0 + w2*32 + mt*16 + qd*4 + r;
                    float rg = sigf(aR0[mt][r] + bR);
                    float zg = sigf(aR1[mt][r] + bZ);
                    float ng = tanh_(aNx[mt][r] + bNx + rg*(aNh[mt][r] + bNh));
                    float hn = (1.f - zg)*ng + zg*hold[mt*4 + r];
                    if (colg >= H_) hn = 0.f;
                    hold[mt*4 + r] = hn;
                    Hb[(size_t)row*512 + colg] = f2bf(hn);
                }
        }
        // ---- recon epilogue ----
        if (!isQg && do_r) {
            #pragma unroll
            for (int mt = 0; mt < 2; ++mt)
                #pragma unroll
                for (int r = 0; r < 4; ++r) {
                    int row = m0 + w2*32 + mt*16 + qd*4 + r;
                    size_t ob = ((size_t)row*T_ + v)*XD_;
                    float a = aC[mt][r];
                    if (colr < XD_)        A.o_rm[ob + colr] = a + brc;
                    else if (colr < 2*XD_) A.o_rs[ob + (colr - XD_)] =
                                               softplus_(a + brc) + 1e-4f;
                }
        }
        // ---- flow epilogue (CU31; all 8 waves execute the barriers) ----
        if (isFlowCU && do_f) {
            __syncthreads();
            float* Sf = (float*)(lds + 55296);   // reuse AsQ: 128x32 f32
            if (isQg) {
                #pragma unroll
                for (int mt = 0; mt < 2; ++mt)
                    #pragma unroll
                    for (int r = 0; r < 4; ++r) {
                        int rowl = w2*32 + mt*16 + qd*4 + r;
                        Sf[rowl*32 + ln]      = aM[mt][r];
                        Sf[rowl*32 + 16 + ln] = aS[mt][r];
                    }
            }
            __syncthreads();
            if (isQg) {
                ushort* Zo = A.zbf + (size_t)(j & 1) * ZS;
                #pragma unroll
                for (int s8 = 0; s8 < 8; ++s8) {
                    int rowl = (gtid >> 4)*8 + s8;
                    int row  = m0 + rowl;
                    float mu = Sf[rowl*32 + zd] + bqm_r;
                    float sd = softplus_(Sf[rowl*32 + 16 + zd] + bqs_r) + 1e-4f;
                    size_t oi = ((size_t)row*T_ + j)*ZD_ + zd;
                    float zk = mu + A.eps[oi]*sd;
                    A.o_zm[oi] = mu;
                    A.o_zs[oi] = sd;
                    float lsum = 0.f;
                    #pragma unroll
                    for (int k = 0; k < 3; ++k) {
                        float th = tanh_(grp16_sum(zk*wvv[k]) + fbv[k]);
                        zk = fmaf(uhv[k], th, zk);
                        float det = 1.f + grp16_sum((1.f - th*th)*wvv[k]*uhv[k]);
                        lsum += logf(fabsf(det) + 1e-6f);
                    }
                    A.o_z[oi] = zk;
                    Zo[(size_t)row*32 + zd]      = f2bf(zk);
                    Zo[(size_t)row*32 + 16 + zd] = 0;
                    ldacc[s8] += lsum;
                    if (j == T_ - 1 && zd == 0) A.o_ld[row] = ldacc[s8];
                }
            }
        }

        if (i < NPHASE - 1)
            cbar32(slots, flag, qc, isLead, (unsigned)(i + 1), tid);
    }
}

// ---------------------------------------------------------------------------
extern "C" void kernel_launch(void* const* d_in, const int* in_sizes, int n_in,
                              void* d_out, int out_size, void* d_ws, size_t ws_size,
                              hipStream_t stream)
{
    (void)in_sizes; (void)n_in; (void)out_size; (void)ws_size;
    float* out = (float*)d_out;

    char* p = (char*)d_ws;
    auto alloc = [&](size_t bytes) { void* r = p; p += (bytes + 255) & ~(size_t)255; return r; };
    const size_t HSb = (size_t)1024 * 512 * sizeof(ushort);
    ushort* hqbf = (ushort*)alloc(2 * HSb);
    ushort* hpbf = (ushort*)alloc(2 * HSb);
    ushort* zbf  = (ushort*)alloc(2 * (size_t)1024 * 32 * sizeof(ushort));
    ushort* Wqg  = (ushort*)alloc((size_t)8 * 32 * 544 * sizeof(ushort));
    ushort* Wpg  = (ushort*)alloc((size_t)8 * 128 * 512 * sizeof(ushort));
    unsigned* bar = (unsigned*)alloc((size_t)8 * 2048 * sizeof(unsigned));

    hipMemsetAsync(bar, 0, (size_t)8 * 2048 * sizeof(unsigned), stream);

    OmniArgs a;
    a.x     = (const float*)d_in[0];
    a.eps   = (const float*)d_in[1];
    a.Wih_q = (const float*)d_in[2];
    a.Whh_q = (const float*)d_in[3];
    a.bih_q = (const float*)d_in[4];
    a.bhh_q = (const float*)d_in[5];
    a.Wqm   = (const float*)d_in[6];
    a.bqm   = (const float*)d_in[7];
    a.Wqs   = (const float*)d_in[8];
    a.bqs   = (const float*)d_in[9];
    a.Wih_p = (const float*)d_in[10];
    a.Whh_p = (const float*)d_in[11];
    a.bih_p = (const float*)d_in[12];
    a.bhh_p = (const float*)d_in[13];
    a.Wpm   = (const float*)d_in[14];
    a.bpm   = (const float*)d_in[15];
    a.Wps   = (const float*)d_in[16];
    a.bps   = (const float*)d_in[17];
    a.fu    = (const float*)d_in[18];
    a.fw    = (const float*)d_in[19];
    a.fb    = (const float*)d_in[20];
    a.hqbf = hqbf; a.hpbf = hpbf; a.zbf = zbf; a.Wqg = Wqg; a.Wpg = Wpg; a.bar = bar;
    a.o_rm = out;
    a.o_rs = out + 3891200;
    a.o_z  = out + 7782400;
    a.o_zm = out + 9420800;
    a.o_zs = out + 11059200;
    a.o_ld = out + 12697600;

    void* kargs[] = { &a };
    hipError_t err = hipLaunchCooperativeKernel((void*)omni_persist, dim3(256), dim3(512),
                                                kargs, 0, stream);
    if (err != hipSuccess) {
        // fallback: plain launch — 256 blocks, 1 block/CU (148 KB LDS), all
        // workgroups co-resident.
        (void)hipGetLastError();
        hipLaunchKernelGGL(omni_persist, dim3(256), dim3(512), 0, stream, a);
    }
}